// Round 3
// baseline (97.464 us; speedup 1.0000x reference)
//
#include <hip/hip_runtime.h>

#define NPTS 16384
#define NSPLIT 256
#define CHUNK (NPTS / NSPLIT)        // 64 sources per chunk
#define TPT 8                        // targets per thread
#define TBLK (NPTS / (256 * TPT))    // 8 target blocks
#define PARTIAL_BYTES ((size_t)NSPLIT * NPTS * sizeof(float))   // 16 MB

// Kernel 0: prepack sources as {-2x, -2y, -2z, ||s||^2} float4 (256 KB in ws).
// Lets nn_min fetch each source point with ONE uniform (scalar-pipe) 16B load.
__global__ __launch_bounds__(256) void nn_pack(const float* __restrict__ src,
                                               float4* __restrict__ packed) {
    const int i = blockIdx.x * 256 + threadIdx.x;
    const float x = src[i * 3 + 0], y = src[i * 3 + 1], z = src[i * 3 + 2];
    packed[i] = make_float4(-2.0f * x, -2.0f * y, -2.0f * z, x * x + y * y + z * z);
}

// Kernel 1: per (target-block, source-chunk) partial MIN of d2 = ||s||^2 - 2 t.s.
// Source points are WAVE-UNIFORM -> read via uniform index from the packed array:
// clang scalarizes these to s_load_dwordx4/x8 (scalar cache, no VALU, no LDS).
// No __shared__, no __syncthreads: block body is a pure FMA/min3 stream
// (56 VALU per source pair, 16 independent chains) that covers SMEM latency.
// Grid 8x256 = 2048 blocks; no LDS -> occupancy is wave-limited (32 waves/CU).
__global__ __launch_bounds__(256) void nn_min(const float4* __restrict__ sp,
                                              const float* __restrict__ tar,
                                              float* __restrict__ ws) {
    const int tid = threadIdx.x;
    const int tb  = blockIdx.x;
    const int sc  = blockIdx.y;
    const int sbase = sc * CHUNK;

    const int t0 = tb * (256 * TPT) + tid;
    float tx[TPT], ty[TPT], tz[TPT], best[TPT];
#pragma unroll
    for (int k = 0; k < TPT; ++k) {
        const int t = t0 + k * 256;
        tx[k] = tar[t * 3 + 0];
        ty[k] = tar[t * 3 + 1];
        tz[k] = tar[t * 3 + 2];
        best[k] = 1e30f;
    }

    // Software-pipelined pair loop: prefetch next pair (scalar loads) while the
    // current pair's 56 VALU ops execute.
    float4 a = sp[sbase + 0];
    float4 b = sp[sbase + 1];
#pragma unroll 2
    for (int j = 0; j < CHUNK - 2; j += 2) {
        float4 na = sp[sbase + j + 2];
        float4 nb = sp[sbase + j + 3];
#pragma unroll
        for (int k = 0; k < TPT; ++k) {
            float d0 = fmaf(tx[k], a.x, fmaf(ty[k], a.y, fmaf(tz[k], a.z, a.w)));
            float d1 = fmaf(tx[k], b.x, fmaf(ty[k], b.y, fmaf(tz[k], b.z, b.w)));
            best[k] = fminf(fminf(d0, d1), best[k]);   // -> v_min3_f32
        }
        a = na; b = nb;
    }
#pragma unroll
    for (int k = 0; k < TPT; ++k) {   // last pair
        float d0 = fmaf(tx[k], a.x, fmaf(ty[k], a.y, fmaf(tz[k], a.z, a.w)));
        float d1 = fmaf(tx[k], b.x, fmaf(ty[k], b.y, fmaf(tz[k], b.z, b.w)));
        best[k] = fminf(fminf(d0, d1), best[k]);
    }

#pragma unroll
    for (int k = 0; k < TPT; ++k)
        ws[sc * NPTS + t0 + k * 256] = best[k];
}

// Kernel 2: reduce NSPLIT partial mins per target, add ||t||^2, sum 0.5*d2 into out.
__global__ __launch_bounds__(256) void nn_sum(const float* __restrict__ tar,
                                              const float* __restrict__ ws,
                                              float* __restrict__ out) {
    const int t = blockIdx.x * 256 + threadIdx.x;
    float b0 = 1e30f, b1 = 1e30f, b2 = 1e30f, b3 = 1e30f;
#pragma unroll 4
    for (int sc = 0; sc < NSPLIT; sc += 8) {
        float v0 = ws[(sc + 0) * NPTS + t];
        float v1 = ws[(sc + 1) * NPTS + t];
        float v2 = ws[(sc + 2) * NPTS + t];
        float v3 = ws[(sc + 3) * NPTS + t];
        float v4 = ws[(sc + 4) * NPTS + t];
        float v5 = ws[(sc + 5) * NPTS + t];
        float v6 = ws[(sc + 6) * NPTS + t];
        float v7 = ws[(sc + 7) * NPTS + t];
        b0 = fminf(fminf(v0, v1), b0);
        b1 = fminf(fminf(v2, v3), b1);
        b2 = fminf(fminf(v4, v5), b2);
        b3 = fminf(fminf(v6, v7), b3);
    }
    float best = fminf(fminf(b0, b1), fminf(b2, b3));
    const float tx = tar[t * 3 + 0], ty = tar[t * 3 + 1], tz = tar[t * 3 + 2];
    float v = 0.5f * (best + tx * tx + ty * ty + tz * tz);   // 0.5*||t-s||^2

    for (int off = 32; off > 0; off >>= 1) v += __shfl_down(v, off, 64);
    __shared__ float wsum[4];
    const int lane = threadIdx.x & 63, wv = threadIdx.x >> 6;
    if (lane == 0) wsum[wv] = v;
    __syncthreads();
    if (threadIdx.x == 0) atomicAdd(out, wsum[0] + wsum[1] + wsum[2] + wsum[3]);
}

// Fallback if d_ws is too small: single kernel, full source sweep in LDS tiles.
__global__ __launch_bounds__(256) void nn_all(const float* __restrict__ src,
                                              const float* __restrict__ tar,
                                              float* __restrict__ out) {
    __shared__ float4 sp[2048];
    const int tid = threadIdx.x;
    const int t = blockIdx.x * 256 + tid;
    const float tx = tar[t * 3 + 0], ty = tar[t * 3 + 1], tz = tar[t * 3 + 2];
    float best = 1e30f;
    for (int base = 0; base < NPTS; base += 2048) {
        __syncthreads();
        for (int i = tid; i < 2048; i += 256) {
            float x = src[(base + i) * 3 + 0];
            float y = src[(base + i) * 3 + 1];
            float z = src[(base + i) * 3 + 2];
            sp[i] = make_float4(-2.0f * x, -2.0f * y, -2.0f * z, x * x + y * y + z * z);
        }
        __syncthreads();
#pragma unroll 4
        for (int j = 0; j < 2048; j += 2) {
            float4 s0 = sp[j];
            float4 s1 = sp[j + 1];
            float d0 = fmaf(tx, s0.x, fmaf(ty, s0.y, fmaf(tz, s0.z, s0.w)));
            float d1 = fmaf(tx, s1.x, fmaf(ty, s1.y, fmaf(tz, s1.z, s1.w)));
            best = fminf(fminf(d0, d1), best);
        }
    }
    float v = 0.5f * (best + tx * tx + ty * ty + tz * tz);
    for (int off = 32; off > 0; off >>= 1) v += __shfl_down(v, off, 64);
    __shared__ float wsum[4];
    const int lane = threadIdx.x & 63, wv = threadIdx.x >> 6;
    if (lane == 0) wsum[wv] = v;
    __syncthreads();
    if (threadIdx.x == 0) atomicAdd(out, wsum[0] + wsum[1] + wsum[2] + wsum[3]);
}

extern "C" void kernel_launch(void* const* d_in, const int* in_sizes, int n_in,
                              void* d_out, int out_size, void* d_ws, size_t ws_size,
                              hipStream_t stream) {
    const float* src = (const float*)d_in[0];
    const float* tar = (const float*)d_in[1];
    float* out = (float*)d_out;

    // Only out[0] needs zeroing for the atomicAdd (the 256 MiB fills in the
    // profile are the HARNESS's ws poison, not ours -- confirmed round 2).
    size_t zero_bytes = (size_t)out_size * sizeof(float);
    if (zero_bytes > 256) zero_bytes = 256;
    hipMemsetAsync(d_out, 0, zero_bytes, stream);

    const size_t need = PARTIAL_BYTES + NPTS * sizeof(float4);   // 16 MB + 256 KB
    if (ws_size >= need) {
        float*  partial = (float*)d_ws;
        float4* packed  = (float4*)((char*)d_ws + PARTIAL_BYTES);
        nn_pack<<<NPTS / 256, 256, 0, stream>>>(src, packed);
        nn_min<<<dim3(TBLK, NSPLIT), 256, 0, stream>>>(packed, tar, partial);
        nn_sum<<<NPTS / 256, 256, 0, stream>>>(tar, partial, out);
    } else {
        nn_all<<<NPTS / 256, 256, 0, stream>>>(src, tar, out);
    }
}

// Round 4
// 80.953 us; speedup vs baseline: 1.2040x; 1.2040x over previous
//
#include <hip/hip_runtime.h>

#define NPTS 16384
#define NSPLIT 64
#define CHUNK (NPTS / NSPLIT)        // 256 sources per chunk
#define TPT 4                        // targets per thread
#define TBLK (NPTS / (256 * TPT))    // 16 target blocks

// Kernel 1: per (target-block, source-chunk) partial MIN of d2 = ||s||^2 - 2 t.s.
// Geometry rationale (r4): NSPLIT=64/TPT=4/CHUNK=256 gives
//   - grid 16x64 = 1024 blocks = 4 blocks/CU,
//   - ~48 VGPR (4 target regs sets, not 8) -> 8 waves/SIMD = FULL 32 waves/CU,
//   - per-wave compute 7168 cyc vs ~800 cyc block overhead (11%, was 22-50%).
// Inner loop is the r1-proven LDS-broadcast form (uniform sp[j] -> ds_read_b128
// broadcast, no bank conflicts); pairs fuse fminf(fminf(d0,d1),best) -> v_min3_f32.
// r3 lesson: do NOT replace LDS broadcast with uniform global/scalar loads (-25%).
__global__ __launch_bounds__(256) void nn_min(const float* __restrict__ src,
                                              const float* __restrict__ tar,
                                              float* __restrict__ ws) {
    __shared__ float4 sp[CHUNK];
    const int tid = threadIdx.x;
    const int tb  = blockIdx.x;
    const int sc  = blockIdx.y;
    const int sbase = sc * CHUNK;

    // Stage chunk as {-2x, -2y, -2z, ||s||^2}: exactly one source per thread.
    {
        const int i = sbase + tid;
        const float x = src[i * 3 + 0];
        const float y = src[i * 3 + 1];
        const float z = src[i * 3 + 2];
        sp[tid] = make_float4(-2.0f * x, -2.0f * y, -2.0f * z, x * x + y * y + z * z);
    }
    __syncthreads();

    const int t0 = tb * (256 * TPT) + tid;
    float tx[TPT], ty[TPT], tz[TPT], best[TPT];
#pragma unroll
    for (int k = 0; k < TPT; ++k) {
        const int t = t0 + k * 256;
        tx[k] = tar[t * 3 + 0];
        ty[k] = tar[t * 3 + 1];
        tz[k] = tar[t * 3 + 2];
        best[k] = 1e30f;
    }

#pragma unroll 4
    for (int j = 0; j < CHUNK; j += 2) {
        float4 s0 = sp[j];
        float4 s1 = sp[j + 1];
#pragma unroll
        for (int k = 0; k < TPT; ++k) {
            float d0 = fmaf(tx[k], s0.x, fmaf(ty[k], s0.y, fmaf(tz[k], s0.z, s0.w)));
            float d1 = fmaf(tx[k], s1.x, fmaf(ty[k], s1.y, fmaf(tz[k], s1.z, s1.w)));
            best[k] = fminf(fminf(d0, d1), best[k]);   // -> v_min3_f32
        }
    }

#pragma unroll
    for (int k = 0; k < TPT; ++k)
        ws[sc * NPTS + t0 + k * 256] = best[k];
}

// Kernel 2: reduce NSPLIT partial mins per target, add ||t||^2, sum 0.5*d2 into out.
__global__ __launch_bounds__(256) void nn_sum(const float* __restrict__ tar,
                                              const float* __restrict__ ws,
                                              float* __restrict__ out) {
    const int t = blockIdx.x * 256 + threadIdx.x;
    float b0 = 1e30f, b1 = 1e30f, b2 = 1e30f, b3 = 1e30f;
#pragma unroll
    for (int sc = 0; sc < NSPLIT; sc += 8) {
        float v0 = ws[(sc + 0) * NPTS + t];
        float v1 = ws[(sc + 1) * NPTS + t];
        float v2 = ws[(sc + 2) * NPTS + t];
        float v3 = ws[(sc + 3) * NPTS + t];
        float v4 = ws[(sc + 4) * NPTS + t];
        float v5 = ws[(sc + 5) * NPTS + t];
        float v6 = ws[(sc + 6) * NPTS + t];
        float v7 = ws[(sc + 7) * NPTS + t];
        b0 = fminf(fminf(v0, v1), b0);
        b1 = fminf(fminf(v2, v3), b1);
        b2 = fminf(fminf(v4, v5), b2);
        b3 = fminf(fminf(v6, v7), b3);
    }
    float best = fminf(fminf(b0, b1), fminf(b2, b3));
    const float tx = tar[t * 3 + 0], ty = tar[t * 3 + 1], tz = tar[t * 3 + 2];
    float v = 0.5f * (best + tx * tx + ty * ty + tz * tz);   // 0.5*||t-s||^2

    for (int off = 32; off > 0; off >>= 1) v += __shfl_down(v, off, 64);
    __shared__ float wsum[4];
    const int lane = threadIdx.x & 63, wv = threadIdx.x >> 6;
    if (lane == 0) wsum[wv] = v;
    __syncthreads();
    if (threadIdx.x == 0) atomicAdd(out, wsum[0] + wsum[1] + wsum[2] + wsum[3]);
}

// Fallback if d_ws is too small (need 4 MB): single kernel, full source sweep.
__global__ __launch_bounds__(256) void nn_all(const float* __restrict__ src,
                                              const float* __restrict__ tar,
                                              float* __restrict__ out) {
    __shared__ float4 sp[2048];
    const int tid = threadIdx.x;
    const int t = blockIdx.x * 256 + tid;
    const float tx = tar[t * 3 + 0], ty = tar[t * 3 + 1], tz = tar[t * 3 + 2];
    float best = 1e30f;
    for (int base = 0; base < NPTS; base += 2048) {
        __syncthreads();
        for (int i = tid; i < 2048; i += 256) {
            float x = src[(base + i) * 3 + 0];
            float y = src[(base + i) * 3 + 1];
            float z = src[(base + i) * 3 + 2];
            sp[i] = make_float4(-2.0f * x, -2.0f * y, -2.0f * z, x * x + y * y + z * z);
        }
        __syncthreads();
#pragma unroll 4
        for (int j = 0; j < 2048; j += 2) {
            float4 s0 = sp[j];
            float4 s1 = sp[j + 1];
            float d0 = fmaf(tx, s0.x, fmaf(ty, s0.y, fmaf(tz, s0.z, s0.w)));
            float d1 = fmaf(tx, s1.x, fmaf(ty, s1.y, fmaf(tz, s1.z, s1.w)));
            best = fminf(fminf(d0, d1), best);
        }
    }
    float v = 0.5f * (best + tx * tx + ty * ty + tz * tz);
    for (int off = 32; off > 0; off >>= 1) v += __shfl_down(v, off, 64);
    __shared__ float wsum[4];
    const int lane = threadIdx.x & 63, wv = threadIdx.x >> 6;
    if (lane == 0) wsum[wv] = v;
    __syncthreads();
    if (threadIdx.x == 0) atomicAdd(out, wsum[0] + wsum[1] + wsum[2] + wsum[3]);
}

extern "C" void kernel_launch(void* const* d_in, const int* in_sizes, int n_in,
                              void* d_out, int out_size, void* d_ws, size_t ws_size,
                              hipStream_t stream) {
    const float* src = (const float*)d_in[0];
    const float* tar = (const float*)d_in[1];
    float* out = (float*)d_out;

    // Only out[0] needs zeroing for the atomicAdd (the 256 MiB fill in the profile
    // is the HARNESS's per-iteration ws poison -- confirmed rounds 2-3, untouchable).
    size_t zero_bytes = (size_t)out_size * sizeof(float);
    if (zero_bytes > 256) zero_bytes = 256;
    hipMemsetAsync(d_out, 0, zero_bytes, stream);

    const size_t need = (size_t)NSPLIT * NPTS * sizeof(float);   // 4 MB
    if (ws_size >= need) {
        nn_min<<<dim3(TBLK, NSPLIT), 256, 0, stream>>>(src, tar, (float*)d_ws);
        nn_sum<<<NPTS / 256, 256, 0, stream>>>(tar, (const float*)d_ws, out);
    } else {
        nn_all<<<NPTS / 256, 256, 0, stream>>>(src, tar, out);
    }
}